// Round 4
// baseline (1424.730 us; speedup 1.0000x reference)
//
#include <hip/hip_runtime.h>
#include <cstdint>
#include <cstddef>

#define B_   32
#define LQ   2048
#define LK   2048
#define DK   64
#define DV   64
#define TQ   16
#define LDP  2056   // padded P row length in bf16 elems; byte stride 4112 = 257*16 (16B-aligned, 2-way-max LDS conflicts)

typedef short bf16x8 __attribute__((ext_vector_type(8)));
typedef float f32x4  __attribute__((ext_vector_type(4)));

// exp(x/8) = exp2(x * log2(e)/8)
#define KSCALE 0.1803368801111204f

__device__ __forceinline__ short f2bf(float f) {          // round-to-nearest-even fp32->bf16
  unsigned u = __builtin_bit_cast(unsigned, f);
  u += 0x7fffu + ((u >> 16) & 1u);
  return (short)(u >> 16);
}

__device__ __forceinline__ bf16x8 pack8(float4 a, float4 b) {
  bf16x8 r;
  r[0]=f2bf(a.x); r[1]=f2bf(a.y); r[2]=f2bf(a.z); r[3]=f2bf(a.w);
  r[4]=f2bf(b.x); r[5]=f2bf(b.y); r[6]=f2bf(b.z); r[7]=f2bf(b.w);
  return r;
}

// Merged-stream design: phase 1 computes exp(QK^T/T), applies mask, and
// streams UNNORMALIZED f32 P straight to attn (normal stores, L2-allocating)
// while NT mask loads flow in — read+write HBM streams active concurrently
// from all waves for ~90% of the kernel (was: phase-gated, <=50% duty each).
// Epilogue: waves 0-3 PV (out = (P@V)*rinv, linearity); waves 4-7 rescale
// attn in place — the 128 KB/block round-trip stays in same-XCD L2/L3
// (512 resident blocks x 128 KB = 64 MB << 256 MB L3), so HBM sees attn
// written only once.
__global__ __launch_bounds__(512, 4) void sdpa_kernel(
    const float* __restrict__ q, const float* __restrict__ k,
    const float* __restrict__ v, const int* __restrict__ mask,
    float* __restrict__ out, float* __restrict__ attn) {
  __shared__ short P[TQ][LDP];     // masked exp(S), bf16 (for PV)
  __shared__ float rowsum[TQ];
  __shared__ float rinv[TQ];

  const int tid  = threadIdx.x;
  const int wave = tid >> 6;       // 0..7
  const int lane = tid & 63;
  const int quad = lane >> 4;      // 0..3
  const int l15  = lane & 15;
  const int b     = blockIdx.y;
  const int qbase = blockIdx.x * TQ;

  if (tid < TQ) rowsum[tid] = 0.0f;
  __syncthreads();

  // ---- Q fragments: A[m=l15][k=quad*8+j] ----
  const float* qr = q + ((size_t)b * LQ + qbase + l15) * DK + quad * 8;
  bf16x8 qa0 = pack8(*(const float4*)(qr),      *(const float4*)(qr + 4));
  bf16x8 qa1 = pack8(*(const float4*)(qr + 32), *(const float4*)(qr + 36));

  // ---- Phase 1: S = Q K^T, p = mask ? 0 : exp(S/temp) ----
  //   -> f32 unnormalized store to attn (normal), bf16 to LDS, rowsums.
  // wave handles n-tiles ntc = wave + 8j, j = 0..15
  const float* kbase = k + (size_t)b * LK * DK + (size_t)l15 * DK + quad * 8;
  const int*   mbase = mask + ((size_t)b * LQ + qbase + quad * 4) * (size_t)LK + l15;
  float*       abase = attn + ((size_t)b * LQ + qbase + quad * 4) * (size_t)LK + l15;
  const f32x4 z4 = {0.f, 0.f, 0.f, 0.f};

  float4 kp0, kp1, kp2, kp3;
  int mp0[4], mp1[4];
  {
    const float* kr = kbase + (size_t)wave * (16 * DK);
    kp0 = *(const float4*)(kr);      kp1 = *(const float4*)(kr + 4);
    kp2 = *(const float4*)(kr + 32); kp3 = *(const float4*)(kr + 36);
    const int* mr0 = mbase + wave * 16;          // tile j=0
    const int* mr1 = mbase + (wave + 8) * 16;    // tile j=1
    #pragma unroll
    for (int r = 0; r < 4; ++r) {
      mp0[r] = __builtin_nontemporal_load(mr0 + (size_t)r * LK);
      mp1[r] = __builtin_nontemporal_load(mr1 + (size_t)r * LK);
    }
  }
  float sum0[4] = {0,0,0,0};
  #pragma unroll 1
  for (int j = 0; j < 16; ++j) {
    float4 kc0 = kp0, kc1 = kp1, kc2 = kp2, kc3 = kp3;
    int mc[4];
    #pragma unroll
    for (int r = 0; r < 4; ++r) { mc[r] = mp0[r]; mp0[r] = mp1[r]; }
    const int ntc = wave + 8 * j;
    if (j < 15) {   // K prefetch depth 1 (L2-resident)
      const float* kr = kbase + (size_t)(ntc + 8) * (16 * DK);
      kp0 = *(const float4*)(kr);      kp1 = *(const float4*)(kr + 4);
      kp2 = *(const float4*)(kr + 32); kp3 = *(const float4*)(kr + 36);
    }
    if (j < 14) {   // mask prefetch depth 2 (HBM latency cover)
      const int* mr = mbase + (ntc + 16) * 16;
      #pragma unroll
      for (int r = 0; r < 4; ++r)
        mp1[r] = __builtin_nontemporal_load(mr + (size_t)r * LK);
    }
    bf16x8 kb0 = pack8(kc0, kc1);   // B[k][n]=K[n][k]: n=l15, k=quad*8+j
    bf16x8 kb1 = pack8(kc2, kc3);
    f32x4 acc0 = __builtin_amdgcn_mfma_f32_16x16x32_bf16(qa0, kb0, z4, 0, 0, 0);
    acc0       = __builtin_amdgcn_mfma_f32_16x16x32_bf16(qa1, kb1, acc0, 0, 0, 0);
    // D[row=quad*4+r][col=l15]
    const int col = ntc * 16 + l15;
    float* ast = abase + ntc * 16;
    #pragma unroll
    for (int r = 0; r < 4; ++r) {
      float p = mc[r] ? 0.0f : __builtin_amdgcn_exp2f(acc0[r] * KSCALE);
      P[quad * 4 + r][col] = f2bf(p);
      ast[(size_t)r * LK] = p;           // unnormalized f32, rescaled in epilogue
      sum0[r] += p;
    }
  }
  // quad-level (16-lane) reduction: each quad owns rows quad*4+r
  #pragma unroll
  for (int r = 0; r < 4; ++r) {
    float s0 = sum0[r];
    #pragma unroll
    for (int off = 1; off < 16; off <<= 1) s0 += __shfl_xor(s0, off);
    if (l15 == 0) atomicAdd(&rowsum[quad * 4 + r], s0);
  }
  __syncthreads();                       // also drains vmcnt: attn stores at L2
  if (tid < TQ) rinv[tid] = 1.0f / rowsum[tid];
  __syncthreads();

  if (wave < 4) {
    // ---- Epilogue A (waves 0-3): O = P V, one 16-col V tile per wave ----
    // depth-2 prefetch of V fragments (V is L2-resident)
    const float* vbase = v + (size_t)b * LK * DV + wave * 16 + l15;
    f32x4 o0 = z4;
    float fva[8], fvb[8];
    #pragma unroll
    for (int j = 0; j < 8; ++j) {
      fva[j] = vbase[(size_t)(quad * 8 + j) * DV];
      fvb[j] = vbase[(size_t)(32 + quad * 8 + j) * DV];
    }
    #pragma unroll 1
    for (int kt = 0; kt < 64; kt += 2) {
      float fc[8];
      #pragma unroll
      for (int j = 0; j < 8; ++j) fc[j] = fva[j];
      if (kt != 62) {
        #pragma unroll
        for (int j = 0; j < 8; ++j)
          fva[j] = vbase[(size_t)((kt + 2) * 32 + quad * 8 + j) * DV];
      }
      bf16x8 bv0;
      #pragma unroll
      for (int j = 0; j < 8; ++j) bv0[j] = f2bf(fc[j]);
      bf16x8 a0 = *(const bf16x8*)&P[l15][kt * 32 + quad * 8];
      o0 = __builtin_amdgcn_mfma_f32_16x16x32_bf16(a0, bv0, o0, 0, 0, 0);

      #pragma unroll
      for (int j = 0; j < 8; ++j) fc[j] = fvb[j];
      if (kt != 62) {
        #pragma unroll
        for (int j = 0; j < 8; ++j)
          fvb[j] = vbase[(size_t)((kt + 3) * 32 + quad * 8 + j) * DV];
      }
      bf16x8 bv1;
      #pragma unroll
      for (int j = 0; j < 8; ++j) bv1[j] = f2bf(fc[j]);
      bf16x8 a1 = *(const bf16x8*)&P[l15][(kt + 1) * 32 + quad * 8];
      o0 = __builtin_amdgcn_mfma_f32_16x16x32_bf16(a1, bv1, o0, 0, 0, 0);
    }
    #pragma unroll
    for (int r = 0; r < 4; ++r) {
      const int row0 = quad * 4 + r;
      out[((size_t)b * LQ + qbase + row0) * DV + wave * 16 + l15] = o0[r] * rinv[row0];
    }
  } else {
    // ---- Epilogue B (waves 4-7): rescale attn in place (L2/L3-resident) ----
    const int ww = wave - 4;
    float* arow = attn + ((size_t)b * LQ + qbase) * (size_t)LK + lane * 4;
    #pragma unroll 1
    for (int j = 0; j < 4; ++j) {
      const int row = ww * 4 + j;
      const float ri = rinv[row];
      float* dst = arow + (size_t)row * LK;
      f32x4 vals[8];
      #pragma unroll
      for (int it = 0; it < 8; ++it)
        vals[it] = *(const f32x4*)(dst + it * 256);
      #pragma unroll
      for (int it = 0; it < 8; ++it) {
        f32x4 vv = vals[it];
        vv[0] *= ri; vv[1] *= ri; vv[2] *= ri; vv[3] *= ri;
        *(f32x4*)(dst + it * 256) = vv;
      }
    }
  }
}

extern "C" void kernel_launch(void* const* d_in, const int* in_sizes, int n_in,
                              void* d_out, int out_size, void* d_ws, size_t ws_size,
                              hipStream_t stream) {
  (void)in_sizes; (void)n_in; (void)out_size; (void)d_ws; (void)ws_size;
  const float* q    = (const float*)d_in[0];
  const float* k    = (const float*)d_in[1];
  const float* v    = (const float*)d_in[2];
  const int*   mask = (const int*)d_in[3];
  float* out  = (float*)d_out;
  float* attn = out + (size_t)B_ * LQ * DV;   // outputs concatenated: (out, attn)
  dim3 grid(LQ / TQ, B_);
  sdpa_kernel<<<grid, 512, 0, stream>>>(q, k, v, mask, out, attn);
}